// Round 10
// baseline (7191.280 us; speedup 1.0000x reference)
//
#include <hip/hip_runtime.h>
#include <hip/hip_bf16.h>
#include <stdint.h>

// LSTM_48601849922171 — 2-layer LSTM (B=8, T=2048, D_IN=256, H=512), fp32 I/O,
// bf16 MFMA compute.
//
// Round 17: R16 base (6916us; steady ~6760) + two chain-latency cuts:
//  1. L0 poll fast path: 2x global_load_dwordx4 sc0 sc1 (MALL-coherent,
//     bypasses L1+L2 like the compiler's system-scope loads) instead of 4
//     unmergeable atomic 8B loads — halves VMEM instructions and MALL
//     transactions per poll round. Every 16th round falls back to the
//     PROVEN atomic-agent path (R10 precedent: passed), so any coherence
//     surprise degrades to ~R12 perf instead of corrupting (guard-capped).
//     Sentinel check per 8B (store is atomic 8B: u64 old xor new; low word
//     ==0xFFFFFFFF iff sentinel since valid bf16 h>=0 has sign bit 0).
//  2. Split MFMA accumulator chains: L0 2x16-deep -> 4x8-deep (acc halves
//     summed after the loop); L1 32-deep -> 2x16-deep. Cuts serial MFMA
//     latency on the critical path ~in half.
// R16 diagnosis recap: backoff on L1 gave +4% => P_L0 binds; congestion is
// minor; remaining period is chain latency (store-vis + detect + compute).
//
// Retained: XCD0 ticket claim (32 tickets; XCD0 spares EXIT; XCD1-7 heat);
// agent-scope store channel, data-as-sentinel; L1 poll with s_sleep backoff;
// 4-wave shared dbuf LDS staging; coalesced quarter fetch; wx prefetch.
//
// Workspace (~111 MB):
//   0:        payl0 [2048][64][16] u64 = 16 MB  (memset 0xFF)
//   16M:      payl1 16 MB                        (memset 0xFF)
//   32M:      Wb0 1MB | 33M: Ub0 2MB | 35M: Wb1 2MB | 37M: Ub1 2MB
//   39M:      wx0 [2048][8][2048] bf16 = 64 MB
//   115343360: done u32, claim u32 (memset 0)

typedef __hip_bfloat16 bf16;
typedef float  floatx4 __attribute__((ext_vector_type(4)));
typedef short  short8  __attribute__((ext_vector_type(8)));
typedef short  short4v __attribute__((ext_vector_type(4)));
typedef unsigned int u32x4 __attribute__((ext_vector_type(4)));
typedef unsigned long long u64;

#define T_STEPS  2048
#define SENT64   0xFFFFFFFFFFFFFFFFull
#define SENT32   0xFFFFFFFFu
#define HH_OFF   8388608   // 8*2048*512
#define CC_OFF   8396800   // HH_OFF + 2*8*512
#define STR0     1056      // LDS row stride bytes, layer 0 ([8][512+pad])
#define STR1     2080      // LDS row stride bytes, layer 1 ([8][1024+pad])
#define BUFSZ    16640     // 8*STR1, one staging buffer slot
#define N_BLK    512
#define N_TICK   32
#define GUARD_MAX (1 << 18)

static __device__ __forceinline__ float bs2f(short s) {
  union { unsigned int u; float f; } c;
  c.u = ((unsigned int)(unsigned short)s) << 16;
  return c.f;
}
static __device__ __forceinline__ short f2bs(float x) {
  union { bf16 h; short s; } u;
  u.h = __float2bfloat16(x);
  return u.s;
}
static __device__ __forceinline__ float sigm(float x) {
  x = fminf(fmaxf(x, -30.f), 30.f);
  return 1.f / (1.f + __expf(-x));
}
static __device__ __forceinline__ float tanhf_(float x) {
  x = fminf(fmaxf(x, -15.f), 15.f);
  float e = __expf(2.f * x);
  return (e - 1.f) / (e + 1.f);
}
static __device__ __forceinline__ floatx4 mfma_bf16(short8 a, short8 b, floatx4 c) {
  return __builtin_amdgcn_mfma_f32_16x16x32_bf16(a, b, c, 0, 0, 0);
}
static __device__ __forceinline__ u64 cload(const u64* p) {
  return __hip_atomic_load(p, __ATOMIC_RELAXED, __HIP_MEMORY_SCOPE_AGENT);
}
static __device__ __forceinline__ void cstore(u64* p, u64 v) {
  __hip_atomic_store(p, v, __ATOMIC_RELAXED, __HIP_MEMORY_SCOPE_AGENT);
}

// L0 HOT poll+fetch of one 8KB payload quarter into the shared LDS image.
// Fast path: 2x dwordx4 sc0 sc1 (MALL-served); every 16th round: proven
// atomic-agent loads (progress guarantee). Detection IS the critical path.
static __device__ __forceinline__ void poll_fetch_q(const u64* paylT, int wv,
                                                    int lane, char* buf,
                                                    int stride, int colOff) {
  const u64* p = paylT + wv * 256 + lane * 4;
  u32x4 A, B;
  int guard = 0;
  for (;;) {
    if ((guard & 15) == 15) {
      u64 q0 = cload(p), q1 = cload(p + 1), q2 = cload(p + 2), q3 = cload(p + 3);
      A.x = (unsigned)q0; A.y = (unsigned)(q0 >> 32);
      A.z = (unsigned)q1; A.w = (unsigned)(q1 >> 32);
      B.x = (unsigned)q2; B.y = (unsigned)(q2 >> 32);
      B.z = (unsigned)q3; B.w = (unsigned)(q3 >> 32);
    } else {
      asm volatile("global_load_dwordx4 %0, %2, off sc0 sc1\n\t"
                   "global_load_dwordx4 %1, %2, off offset:16 sc0 sc1\n\t"
                   "s_waitcnt vmcnt(0)"
                   : "=&v"(A), "=&v"(B) : "v"(p) : "memory");
    }
    int ok = (A.x != SENT32) & (A.z != SENT32) & (B.x != SENT32) & (B.z != SENT32);
    if (__all(ok)) break;
    if (++guard > GUARD_MAX) break;
  }
  char* base = buf + colOff + wv * 256 + (lane >> 2) * 16;
  const int r0 = (lane & 3) * 2;
  *reinterpret_cast<u32x4*>(base + (long)r0 * stride)       = A;  // q0|q1
  *reinterpret_cast<u32x4*>(base + (long)(r0 + 1) * stride) = B;  // q2|q3
}
// L1 fused dual-quarter poll (payl0[t] + payl1[t-1], one spin) with s_sleep
// backoff — off the critical path (R16-proven, +4%).
static __device__ __forceinline__ void poll_fetch_q2(const u64* p0T, const u64* p1T,
                                                     int wv, int lane, char* buf) {
  const u64* p0 = p0T + wv * 256 + lane * 4;
  const u64* p1 = p1T + wv * 256 + lane * 4;
  u64 a0, a1, a2, a3, b0, b1, b2, b3;
  int guard = 0;
  for (;;) {
    a0 = cload(p0);     a1 = cload(p0 + 1);
    a2 = cload(p0 + 2); a3 = cload(p0 + 3);
    b0 = cload(p1);     b1 = cload(p1 + 1);
    b2 = cload(p1 + 2); b3 = cload(p1 + 3);
    int ok = (a0 != SENT64) & (a1 != SENT64) & (a2 != SENT64) & (a3 != SENT64) &
             (b0 != SENT64) & (b1 != SENT64) & (b2 != SENT64) & (b3 != SENT64);
    if (__all(ok)) break;
    if (++guard > GUARD_MAX) break;
    __builtin_amdgcn_s_sleep(4);   // ~256cy backoff, off critical path
  }
  char* base0 = buf + wv * 256 + (lane >> 2) * 16;
  const int r0 = (lane & 3) * 2;
  *reinterpret_cast<u64*>(base0 + (long)r0 * STR1)           = a0;
  *reinterpret_cast<u64*>(base0 + (long)r0 * STR1 + 8)       = a1;
  *reinterpret_cast<u64*>(base0 + (long)(r0 + 1) * STR1)     = a2;
  *reinterpret_cast<u64*>(base0 + (long)(r0 + 1) * STR1 + 8) = a3;
  char* base1 = base0 + 1024;
  *reinterpret_cast<u64*>(base1 + (long)r0 * STR1)           = b0;
  *reinterpret_cast<u64*>(base1 + (long)r0 * STR1 + 8)       = b1;
  *reinterpret_cast<u64*>(base1 + (long)(r0 + 1) * STR1)     = b2;
  *reinterpret_cast<u64*>(base1 + (long)(r0 + 1) * STR1 + 8) = b3;
}

// fp32 -> bf16 elementwise (n multiple of 4)
__global__ __launch_bounds__(256)
void cvt_f32_bf16(const float* __restrict__ src, bf16* __restrict__ dst, int n) {
  int i = (blockIdx.x * 256 + threadIdx.x) * 4;
  if (i < n) {
    floatx4 v = *reinterpret_cast<const floatx4*>(src + i);
    short4v o;
    #pragma unroll
    for (int r = 0; r < 4; ++r) o[r] = f2bs(v[r]);
    *reinterpret_cast<short4v*>(dst + i) = o;
  }
}

// ---------------------------------------------------------------------------
// Layer-0 input projection (unchanged).
// ---------------------------------------------------------------------------
__global__ __launch_bounds__(256)
void gemm_proj(const float* __restrict__ Af, const bf16* __restrict__ W,
               const float* __restrict__ bias, bf16* __restrict__ out,
               int K, int strideB, int strideT)
{
  const int lane  = threadIdx.x & 63;
  const int wave  = threadIdx.x >> 6;
  const int q     = lane >> 4;
  const int c     = lane & 15;
  const int mtile = blockIdx.x;
  const int nbase = blockIdx.y * 256 + wave * 64;
  const int m     = mtile * 16 + c;

  const long abase = (long)(m & 7) * strideB + (long)(m >> 3) * strideT + q * 8;
  const bf16* W0 = W + (long)(nbase +  0 + c) * K + q * 8;
  const bf16* W1 = W + (long)(nbase + 16 + c) * K + q * 8;
  const bf16* W2 = W + (long)(nbase + 32 + c) * K + q * 8;
  const bf16* W3 = W + (long)(nbase + 48 + c) * K + q * 8;

  floatx4 acc0 = {0.f, 0.f, 0.f, 0.f};
  floatx4 acc1 = acc0, acc2 = acc0, acc3 = acc0;
  const int nk = K >> 5;
  for (int kt = 0; kt < nk; ++kt) {
    short8 a;
    floatx4 lo = *reinterpret_cast<const floatx4*>(Af + abase + kt * 32);
    floatx4 hi = *reinterpret_cast<const floatx4*>(Af + abase + kt * 32 + 4);
    #pragma unroll
    for (int r = 0; r < 4; ++r) { a[r] = f2bs(lo[r]); a[4 + r] = f2bs(hi[r]); }
    short8 b0 = *reinterpret_cast<const short8*>(W0 + kt * 32);
    short8 b1 = *reinterpret_cast<const short8*>(W1 + kt * 32);
    short8 b2 = *reinterpret_cast<const short8*>(W2 + kt * 32);
    short8 b3 = *reinterpret_cast<const short8*>(W3 + kt * 32);
    acc0 = mfma_bf16(a, b0, acc0);
    acc1 = mfma_bf16(a, b1, acc1);
    acc2 = mfma_bf16(a, b2, acc2);
    acc3 = mfma_bf16(a, b3, acc3);
  }

  floatx4 accs[4] = {acc0, acc1, acc2, acc3};
  #pragma unroll
  for (int nt = 0; nt < 4; ++nt) {
    const int n = nbase + nt * 16 + c;
    const float bv = bias[n];
    #pragma unroll
    for (int r = 0; r < 4; ++r) {
      const int mrow = mtile * 16 + q * 4 + r;
      out[(long)mrow * 2048 + n] = __float2bfloat16(accs[nt][r] + bv);
    }
  }
}

// ---------------------------------------------------------------------------
// Fused 2-layer persistent recurrence, XCD0-clustered. 512 blocks x 256 thr.
// XCD0: 32 blocks claim tickets (16 L0 + 16 L1), the rest EXIT (frees CUs).
// XCD1-7: heater blocks (DVFS insurance), poll done every ~14us.
// ---------------------------------------------------------------------------
__global__ __launch_bounds__(256)
void lstm_fused(const bf16* __restrict__ wx, const bf16* __restrict__ Ub0,
                const bf16* __restrict__ Wb1, const bf16* __restrict__ Ub1,
                const float* __restrict__ ub0, const float* __restrict__ w1b,
                const float* __restrict__ u1b, float* __restrict__ out,
                u64* __restrict__ payl0, u64* __restrict__ payl1,
                unsigned int* __restrict__ done, unsigned int* __restrict__ claim)
{
  __shared__ char lds[2 * BUFSZ];   // double-buffered shared h staging
  __shared__ int s_ticket;
  if (threadIdx.x == 0) {
    int xcd = 0;
    asm volatile("s_getreg_b32 %0, hwreg(HW_REG_XCC_ID)" : "=s"(xcd));
    int tk = -1;                                 // default: heater (XCD1-7)
    if ((xcd & 7) == 0) {
      unsigned int t = __hip_atomic_fetch_add(claim, 1u, __ATOMIC_RELAXED,
                                              __HIP_MEMORY_SCOPE_AGENT);
      tk = (t < (unsigned)N_TICK) ? (int)t : -2; // XCD0 spare: exit
    }
    s_ticket = tk;
  }
  __syncthreads();
  const int ticket = s_ticket;

  if (ticket == -2) return;   // XCD0 spare block: free the CU for rec waves

  if (ticket < 0) {
    // ---------------- heater (XCD1-7 blocks only) ----------------
    float a0 = (float)threadIdx.x, a1 = a0 + 1.f, a2 = a0 + 2.f, a3 = a0 + 3.f;
    float a4 = a0 + 4.f, a5 = a0 + 5.f, a6 = a0 + 6.f, a7 = a0 + 7.f;
    const float xm = 1.0000001f, ya = 1e-7f;
    int g = 0;
    for (;;) {
      #pragma unroll
      for (int it = 0; it < 64; ++it) {
        asm volatile("v_fmac_f32 %0, %1, %2" : "+v"(a0) : "v"(xm), "v"(ya));
        asm volatile("v_fmac_f32 %0, %1, %2" : "+v"(a1) : "v"(xm), "v"(ya));
        asm volatile("v_fmac_f32 %0, %1, %2" : "+v"(a2) : "v"(xm), "v"(ya));
        asm volatile("v_fmac_f32 %0, %1, %2" : "+v"(a3) : "v"(xm), "v"(ya));
        asm volatile("v_fmac_f32 %0, %1, %2" : "+v"(a4) : "v"(xm), "v"(ya));
        asm volatile("v_fmac_f32 %0, %1, %2" : "+v"(a5) : "v"(xm), "v"(ya));
        asm volatile("v_fmac_f32 %0, %1, %2" : "+v"(a6) : "v"(xm), "v"(ya));
        asm volatile("v_fmac_f32 %0, %1, %2" : "+v"(a7) : "v"(xm), "v"(ya));
      }
      ++g;
      if ((g & 31) == 0) {           // poll rarely: keeps the MALL line quiet
        if (__hip_atomic_load(done, __ATOMIC_RELAXED,
                              __HIP_MEMORY_SCOPE_AGENT) >= (unsigned)N_TICK) break;
      }
      if (g > (1 << 16)) break;
    }
    return;
  }

  // ---------------- recurrence (4 waves of the 32 claimed blocks) ----------
  asm volatile("s_setprio 3" ::: "memory");
  const int wv    = threadIdx.x >> 6;
  const int lane  = threadIdx.x & 63;
  const int q     = lane >> 4;
  const int b     = lane & 15;
  const int layer = ticket >> 4;          // 0..1
  const int grp   = ticket & 15;          // 0..15
  const int blk   = grp * 4 + wv;         // 0..63
  const int jbase = blk * 8;
  const int jj    = jbase + (q & 1) * 4;

  const int row0 = (b < 8) ? (jbase + b) : (512 + jbase + b - 8);           // i | f
  const int row1 = (b < 8) ? (1024 + jbase + b) : (1536 + jbase + b - 8);   // g | o

  float* hh = out + ((layer == 0) ? HH_OFF : HH_OFF + 4096);
  float* cc = out + ((layer == 0) ? CC_OFF : CC_OFF + 4096);

  if (layer == 0) {
    // ---- Layer 0: K=512 (U0 * h1(t-1)) + precomputed wx ----
    short8 a0[16], a1[16];
    {
      const bf16* U0p = Ub0 + (long)row0 * 512 + q * 8;
      const bf16* U1p = Ub0 + (long)row1 * 512 + q * 8;
      #pragma unroll
      for (int kt = 0; kt < 16; ++kt) {
        a0[kt] = *reinterpret_cast<const short8*>(U0p + kt * 32);
        a1[kt] = *reinterpret_cast<const short8*>(U1p + kt * 32);
      }
    }
    float ubi[4], ubf[4], ubg[4], ubo[4];
    #pragma unroll
    for (int r = 0; r < 4; ++r) {
      ubi[r] = ub0[        jj + r];
      ubf[r] = ub0[ 512 + jj + r];
      ubg[r] = ub0[1024 + jj + r];
      ubo[r] = ub0[1536 + jj + r];
    }
    float cst[4] = {0.f, 0.f, 0.f, 0.f};

    // wx prefetch pipeline: regs hold step t while loop body issues t+1.
    const bf16* wxbase = wx + (b & 7) * 2048 + jj;
    short4v vi = *reinterpret_cast<const short4v*>(wxbase);
    short4v vf = *reinterpret_cast<const short4v*>(wxbase + 512);
    short4v vg = *reinterpret_cast<const short4v*>(wxbase + 1024);
    short4v vo = *reinterpret_cast<const short4v*>(wxbase + 1536);

    for (int t = 0; t < T_STEPS; ++t) {
      float wxi[4], wxf[4], wxg[4], wxo[4];
      #pragma unroll
      for (int r = 0; r < 4; ++r) {
        wxi[r] = bs2f(vi[r]); wxf[r] = bs2f(vf[r]);
        wxg[r] = bs2f(vg[r]); wxo[r] = bs2f(vo[r]);
      }
      if (t + 1 < T_STEPS) {
        const bf16* wn = wxbase + (long)(t + 1) * 16384;
        vi = *reinterpret_cast<const short4v*>(wn);
        vf = *reinterpret_cast<const short4v*>(wn + 512);
        vg = *reinterpret_cast<const short4v*>(wn + 1024);
        vo = *reinterpret_cast<const short4v*>(wn + 1536);
      }

      char* buf = lds + (t & 1) * BUFSZ;
      floatx4 acc0 = {0.f, 0.f, 0.f, 0.f};
      floatx4 acc1 = {0.f, 0.f, 0.f, 0.f};

      if (t > 0)
        poll_fetch_q(payl0 + (long)(t - 1) * 1024, wv, lane, buf, STR0, 0);
      __syncthreads();
      if (t > 0) {
        // 4 independent chains x depth 8 (was 2 x 16) — cuts serial MFMA
        // latency on the critical path.
        floatx4 acc0b = {0.f, 0.f, 0.f, 0.f};
        floatx4 acc1b = {0.f, 0.f, 0.f, 0.f};
        #pragma unroll
        for (int kt = 0; kt < 8; ++kt) {
          short8 hbA = *reinterpret_cast<const short8*>(
              buf + (b & 7) * STR0 + kt * 64 + q * 16);
          short8 hbB = *reinterpret_cast<const short8*>(
              buf + (b & 7) * STR0 + (kt + 8) * 64 + q * 16);
          acc0  = mfma_bf16(a0[kt],     hbA, acc0);
          acc1  = mfma_bf16(a1[kt],     hbA, acc1);
          acc0b = mfma_bf16(a0[kt + 8], hbB, acc0b);
          acc1b = mfma_bf16(a1[kt + 8], hbB, acc1b);
        }
        #pragma unroll
        for (int r = 0; r < 4; ++r) { acc0[r] += acc0b[r]; acc1[r] += acc1b[r]; }
      }

      float fsh[4], osh[4];
      #pragma unroll
      for (int r = 0; r < 4; ++r) {
        fsh[r] = __shfl_xor(acc0[r], 32, 64);
        osh[r] = __shfl_xor(acc1[r], 32, 64);
      }

      if (q < 2 && b < 8) {
        short4v hp4; floatx4 hf4, cf4;
        #pragma unroll
        for (int r = 0; r < 4; ++r) {
          const float pi = acc0[r] + wxi[r] + ubi[r];
          const float pf = fsh[r]  + wxf[r] + ubf[r];
          const float pg = acc1[r] + wxg[r] + ubg[r];
          const float po = osh[r]  + wxo[r] + ubo[r];
          const float it = sigm(pi), ft = sigm(pf);
          const float gt = tanhf_(pg), ot = sigm(po);
          const float cv = ft * cst[r] + it * gt;
          cst[r] = cv;
          const float hv = ot * fmaxf(cv, 0.f);
          hf4[r] = hv; cf4[r] = cv; hp4[r] = f2bs(hv);
        }
        union { short4v v; u64 u; } pk; pk.v = hp4;
        cstore(payl0 + (long)t * 1024 + blk * 16 + (b * 2 + (q & 1)), pk.u);
        if (t == T_STEPS - 1) {
          *reinterpret_cast<floatx4*>(hh + b * 512 + jj) = hf4;
          *reinterpret_cast<floatx4*>(cc + b * 512 + jj) = cf4;
        }
      }
    }
  } else {
    // ---- Layer 1: K=1024 ([W1|U1] * [h1(t); h2(t-1)]) ----
    short8 a0[32], a1[32];
    {
      const bf16* W0p = Wb1 + (long)row0 * 512 + q * 8;
      const bf16* W1p = Wb1 + (long)row1 * 512 + q * 8;
      const bf16* U0p = Ub1 + (long)row0 * 512 + q * 8;
      const bf16* U1p = Ub1 + (long)row1 * 512 + q * 8;
      #pragma unroll
      for (int kt = 0; kt < 16; ++kt) {
        a0[kt]      = *reinterpret_cast<const short8*>(W0p + kt * 32);
        a1[kt]      = *reinterpret_cast<const short8*>(W1p + kt * 32);
        a0[16 + kt] = *reinterpret_cast<const short8*>(U0p + kt * 32);
        a1[16 + kt] = *reinterpret_cast<const short8*>(U1p + kt * 32);
      }
    }
    float ubi[4], ubf[4], ubg[4], ubo[4];
    #pragma unroll
    for (int r = 0; r < 4; ++r) {
      ubi[r] = w1b[        jj + r] + u1b[        jj + r];
      ubf[r] = w1b[ 512 + jj + r] + u1b[ 512 + jj + r];
      ubg[r] = w1b[1024 + jj + r] + u1b[1024 + jj + r];
      ubo[r] = w1b[1536 + jj + r] + u1b[1536 + jj + r];
    }
    float cst[4] = {0.f, 0.f, 0.f, 0.f};

    for (int t = 0; t < T_STEPS; ++t) {
      char* buf = lds + (t & 1) * BUFSZ;
      floatx4 acc0 = {0.f, 0.f, 0.f, 0.f};
      floatx4 acc1 = {0.f, 0.f, 0.f, 0.f};
      floatx4 acc0b = {0.f, 0.f, 0.f, 0.f};
      floatx4 acc1b = {0.f, 0.f, 0.f, 0.f};

      if (t > 0) {
        poll_fetch_q2(payl0 + (long)t * 1024, payl1 + (long)(t - 1) * 1024,
                      wv, lane, buf);
      } else {
        poll_fetch_q(payl0, wv, lane, buf, STR1, 0);
      }
      __syncthreads();

      #pragma unroll
      for (int kt = 0; kt < 16; ++kt) {
        short8 hb = *reinterpret_cast<const short8*>(
            buf + (b & 7) * STR1 + kt * 64 + q * 16);
        acc0 = mfma_bf16(a0[kt], hb, acc0);
        acc1 = mfma_bf16(a1[kt], hb, acc1);
      }
      if (t > 0) {
        // second half into independent accumulators (2x16 chains, was 32)
        #pragma unroll
        for (int kt = 16; kt < 32; ++kt) {
          short8 hb = *reinterpret_cast<const short8*>(
              buf + (b & 7) * STR1 + kt * 64 + q * 16);
          acc0b = mfma_bf16(a0[kt], hb, acc0b);
          acc1b = mfma_bf16(a1[kt], hb, acc1b);
        }
        #pragma unroll
        for (int r = 0; r < 4; ++r) { acc0[r] += acc0b[r]; acc1[r] += acc1b[r]; }
      }

      float fsh[4], osh[4];
      #pragma unroll
      for (int r = 0; r < 4; ++r) {
        fsh[r] = __shfl_xor(acc0[r], 32, 64);
        osh[r] = __shfl_xor(acc1[r], 32, 64);
      }

      if (q < 2 && b < 8) {
        short4v hp4; floatx4 hf4, cf4;
        #pragma unroll
        for (int r = 0; r < 4; ++r) {
          const float pi = acc0[r] + ubi[r];
          const float pf = fsh[r]  + ubf[r];
          const float pg = acc1[r] + ubg[r];
          const float po = osh[r]  + ubo[r];
          const float it = sigm(pi), ft = sigm(pf);
          const float gt = tanhf_(pg), ot = sigm(po);
          const float cv = ft * cst[r] + it * gt;
          cst[r] = cv;
          const float hv = ot * fmaxf(cv, 0.f);
          hf4[r] = hv; cf4[r] = cv; hp4[r] = f2bs(hv);
        }
        union { short4v v; u64 u; } pk; pk.v = hp4;
        cstore(payl1 + (long)t * 1024 + blk * 16 + (b * 2 + (q & 1)), pk.u);
        *reinterpret_cast<floatx4*>(out + (long)b * 1048576 + (long)t * 512 + jj) = hf4;
        if (t == T_STEPS - 1) {
          *reinterpret_cast<floatx4*>(hh + b * 512 + jj) = hf4;
          *reinterpret_cast<floatx4*>(cc + b * 512 + jj) = cf4;
        }
      }
    }
  }

  // Signal heaters to exit (one per rec block).
  __syncthreads();
  if (threadIdx.x == 0) {
    __hip_atomic_fetch_add(done, 1u, __ATOMIC_RELAXED, __HIP_MEMORY_SCOPE_AGENT);
  }
}

extern "C" void kernel_launch(void* const* d_in, const int* in_sizes, int n_in,
                              void* d_out, int out_size, void* d_ws, size_t ws_size,
                              hipStream_t stream) {
  (void)in_sizes; (void)n_in; (void)out_size; (void)ws_size;
  const float* x   = (const float*)d_in[0];
  const float* w0w = (const float*)d_in[1];
  const float* w0b = (const float*)d_in[2];
  const float* u0w = (const float*)d_in[3];
  const float* u0b = (const float*)d_in[4];
  const float* w1w = (const float*)d_in[5];
  const float* w1b = (const float*)d_in[6];
  const float* u1w = (const float*)d_in[7];
  const float* u1b = (const float*)d_in[8];
  float* out = (float*)d_out;

  char* ws = (char*)d_ws;
  u64*  payl0 = (u64*)ws;
  u64*  payl1 = (u64*)(ws + (size_t)16777216);
  bf16* Wb0 = (bf16*)(ws + (size_t)33554432);
  bf16* Ub0 = (bf16*)(ws + (size_t)34603008);
  bf16* Wb1 = (bf16*)(ws + (size_t)36700160);
  bf16* Ub1 = (bf16*)(ws + (size_t)38797312);
  bf16* wx  = (bf16*)(ws + (size_t)40894464);
  unsigned int* done = (unsigned int*)(ws + (size_t)115343360);

  // Sentinel-fill payload arrays; zero the done+claim counters.
  hipMemsetAsync(ws, 0xFF, (size_t)33554432, stream);
  hipMemsetAsync(done, 0, 64, stream);

  // Weight conversions fp32 -> bf16.
  cvt_f32_bf16<<<512,  256, 0, stream>>>(w0w, Wb0, 524288);
  cvt_f32_bf16<<<1024, 256, 0, stream>>>(u0w, Ub0, 1048576);
  cvt_f32_bf16<<<1024, 256, 0, stream>>>(w1w, Wb1, 1048576);
  cvt_f32_bf16<<<1024, 256, 0, stream>>>(u1w, Ub1, 1048576);

  // Layer-0 input projection.
  dim3 gg(1024, 8, 1);
  gemm_proj<<<gg, 256, 0, stream>>>(x, Wb0, w0b, wx, 256, 2048 * 256, 256);

  // Fused 2-layer recurrence (XCD0 rec, XCD1-7 heat) + heaters.
  lstm_fused<<<N_BLK, 256, 0, stream>>>(wx, Ub0, Wb1, Ub1, u0b, w1b, u1b,
                                        out, payl0, payl1, done, done + 1);
}

// Round 12
// 6912.154 us; speedup vs baseline: 1.0404x; 1.0404x over previous
//
#include <hip/hip_runtime.h>
#include <hip/hip_bf16.h>
#include <stdint.h>

// LSTM_48601849922171 — 2-layer LSTM (B=8, T=2048, D_IN=256, H=512), fp32 I/O,
// bf16 MFMA compute.
//
// Round 19 = R18 resubmission. R18's bench died with "MI355X container failed
// twice" — infra failure, no test verdict (same mode as Round 6, which ran
// clean on resubmission). This source is byte-identical to the R16 kernel
// that PASSED in Round 9 at 6916us (best verified), so no code suspect.
//
// Final diagnosis of the remaining period (P_L0 ~ 3.3us/step): agent-scope
// store -> MALL visibility -> detect cycle, where each step's period is the
// MAX over 64 waves' skew (each wave waits on 16 producers), not the mean.
// Falsified levers: L1 weight residency (R13), heater contention (R15),
// poll instruction count (R17), MFMA chain depth (R17). Minor lever: L1 poll
// backoff (+4%, kept). Structural alternatives (batch-partitioned recurrence,
// single-block L0, L2-local channel, per-slice pipelined consumption) are
// infeasible or cost-neutral on this architecture.
//
// Kernel structure (R12/R15/R16 lineage, all verified):
//   - XCD0 ticket claim via HW_REG_XCC_ID (32 tickets: 16 L0 + 16 L1 blocks
//     x 4 waves); XCD0 spare blocks EXIT (free CUs); XCD1-7 blocks run an
//     FMA heater (DVFS insurance) polling `done` every ~14us.
//   - Pure agent-scope channel: producer agent-relaxed 8B store of packed
//     h (data-as-sentinel, payload pre-filled 0xFF); consumer agent-relaxed
//     coalesced poll (4x8B per lane) every iteration. No flag round trip.
//   - 4-wave shared double-buffered LDS staging; each wave polls+fetches a
//     2KB quarter; one barrier/step; MFMA from shared LDS image.
//   - L1 poll: fused dual spin (payl0[t] + payl1[t-1]) with s_sleep(4)
//     backoff — L1 detection is off the critical path (R16: +4%).
//   - wx one-step register prefetch in L0.
//
// Workspace (~111 MB):
//   0:        payl0 [2048][64][16] u64 = 16 MB  (memset 0xFF)
//   16M:      payl1 16 MB                        (memset 0xFF)
//   32M:      Wb0 1MB | 33M: Ub0 2MB | 35M: Wb1 2MB | 37M: Ub1 2MB
//   39M:      wx0 [2048][8][2048] bf16 = 64 MB
//   115343360: done u32, claim u32 (memset 0)

typedef __hip_bfloat16 bf16;
typedef float  floatx4 __attribute__((ext_vector_type(4)));
typedef short  short8  __attribute__((ext_vector_type(8)));
typedef short  short4v __attribute__((ext_vector_type(4)));
typedef unsigned long long u64;

#define T_STEPS  2048
#define SENT64   0xFFFFFFFFFFFFFFFFull
#define HH_OFF   8388608   // 8*2048*512
#define CC_OFF   8396800   // HH_OFF + 2*8*512
#define STR0     1056      // LDS row stride bytes, layer 0 ([8][512+pad])
#define STR1     2080      // LDS row stride bytes, layer 1 ([8][1024+pad])
#define BUFSZ    16640     // 8*STR1, one staging buffer slot
#define N_BLK    512
#define N_TICK   32
#define GUARD_MAX (1 << 18)

static __device__ __forceinline__ float bs2f(short s) {
  union { unsigned int u; float f; } c;
  c.u = ((unsigned int)(unsigned short)s) << 16;
  return c.f;
}
static __device__ __forceinline__ short f2bs(float x) {
  union { bf16 h; short s; } u;
  u.h = __float2bfloat16(x);
  return u.s;
}
static __device__ __forceinline__ float sigm(float x) {
  x = fminf(fmaxf(x, -30.f), 30.f);
  return 1.f / (1.f + __expf(-x));
}
static __device__ __forceinline__ float tanhf_(float x) {
  x = fminf(fmaxf(x, -15.f), 15.f);
  float e = __expf(2.f * x);
  return (e - 1.f) / (e + 1.f);
}
static __device__ __forceinline__ floatx4 mfma_bf16(short8 a, short8 b, floatx4 c) {
  return __builtin_amdgcn_mfma_f32_16x16x32_bf16(a, b, c, 0, 0, 0);
}
static __device__ __forceinline__ u64 cload(const u64* p) {
  return __hip_atomic_load(p, __ATOMIC_RELAXED, __HIP_MEMORY_SCOPE_AGENT);
}
static __device__ __forceinline__ void cstore(u64* p, u64 v) {
  __hip_atomic_store(p, v, __ATOMIC_RELAXED, __HIP_MEMORY_SCOPE_AGENT);
}

// Per-wave quarter poll+fetch of one 8KB payload into the shared LDS image.
// HOT poll (no backoff) — used by L0, whose detection IS the critical path.
static __device__ __forceinline__ void poll_fetch_q(const u64* paylT, int wv,
                                                    int lane, char* buf,
                                                    int stride, int colOff) {
  const u64* p = paylT + wv * 256 + lane * 4;
  u64 q0, q1, q2, q3;
  int guard = 0;
  for (;;) {
    q0 = cload(p);     q1 = cload(p + 1);
    q2 = cload(p + 2); q3 = cload(p + 3);
    int ok = (q0 != SENT64) & (q1 != SENT64) & (q2 != SENT64) & (q3 != SENT64);
    if (__all(ok)) break;
    if (++guard > GUARD_MAX) break;
  }
  char* base = buf + colOff + wv * 256 + (lane >> 2) * 16;
  const int r0 = (lane & 3) * 2;
  *reinterpret_cast<u64*>(base + (long)r0 * stride)           = q0;
  *reinterpret_cast<u64*>(base + (long)r0 * stride + 8)       = q1;
  *reinterpret_cast<u64*>(base + (long)(r0 + 1) * stride)     = q2;
  *reinterpret_cast<u64*>(base + (long)(r0 + 1) * stride + 8) = q3;
}
// Fused dual-quarter poll for layer 1 (payl0[t] and payl1[t-1], one spin).
// BACKOFF poll: s_sleep(4) (~256cy) after each failed round — L1's detection
// is off the critical path (it lags and self-regulates); this cuts L1's
// share of the MALL poll traffic that queues up the L0 chain's RTs.
static __device__ __forceinline__ void poll_fetch_q2(const u64* p0T, const u64* p1T,
                                                     int wv, int lane, char* buf) {
  const u64* p0 = p0T + wv * 256 + lane * 4;
  const u64* p1 = p1T + wv * 256 + lane * 4;
  u64 a0, a1, a2, a3, b0, b1, b2, b3;
  int guard = 0;
  for (;;) {
    a0 = cload(p0);     a1 = cload(p0 + 1);
    a2 = cload(p0 + 2); a3 = cload(p0 + 3);
    b0 = cload(p1);     b1 = cload(p1 + 1);
    b2 = cload(p1 + 2); b3 = cload(p1 + 3);
    int ok = (a0 != SENT64) & (a1 != SENT64) & (a2 != SENT64) & (a3 != SENT64) &
             (b0 != SENT64) & (b1 != SENT64) & (b2 != SENT64) & (b3 != SENT64);
    if (__all(ok)) break;
    if (++guard > GUARD_MAX) break;
    __builtin_amdgcn_s_sleep(4);   // ~256cy backoff, off critical path
  }
  char* base0 = buf + wv * 256 + (lane >> 2) * 16;
  const int r0 = (lane & 3) * 2;
  *reinterpret_cast<u64*>(base0 + (long)r0 * STR1)           = a0;
  *reinterpret_cast<u64*>(base0 + (long)r0 * STR1 + 8)       = a1;
  *reinterpret_cast<u64*>(base0 + (long)(r0 + 1) * STR1)     = a2;
  *reinterpret_cast<u64*>(base0 + (long)(r0 + 1) * STR1 + 8) = a3;
  char* base1 = base0 + 1024;
  *reinterpret_cast<u64*>(base1 + (long)r0 * STR1)           = b0;
  *reinterpret_cast<u64*>(base1 + (long)r0 * STR1 + 8)       = b1;
  *reinterpret_cast<u64*>(base1 + (long)(r0 + 1) * STR1)     = b2;
  *reinterpret_cast<u64*>(base1 + (long)(r0 + 1) * STR1 + 8) = b3;
}

// fp32 -> bf16 elementwise (n multiple of 4)
__global__ __launch_bounds__(256)
void cvt_f32_bf16(const float* __restrict__ src, bf16* __restrict__ dst, int n) {
  int i = (blockIdx.x * 256 + threadIdx.x) * 4;
  if (i < n) {
    floatx4 v = *reinterpret_cast<const floatx4*>(src + i);
    short4v o;
    #pragma unroll
    for (int r = 0; r < 4; ++r) o[r] = f2bs(v[r]);
    *reinterpret_cast<short4v*>(dst + i) = o;
  }
}

// ---------------------------------------------------------------------------
// Layer-0 input projection (unchanged).
// ---------------------------------------------------------------------------
__global__ __launch_bounds__(256)
void gemm_proj(const float* __restrict__ Af, const bf16* __restrict__ W,
               const float* __restrict__ bias, bf16* __restrict__ out,
               int K, int strideB, int strideT)
{
  const int lane  = threadIdx.x & 63;
  const int wave  = threadIdx.x >> 6;
  const int q     = lane >> 4;
  const int c     = lane & 15;
  const int mtile = blockIdx.x;
  const int nbase = blockIdx.y * 256 + wave * 64;
  const int m     = mtile * 16 + c;

  const long abase = (long)(m & 7) * strideB + (long)(m >> 3) * strideT + q * 8;
  const bf16* W0 = W + (long)(nbase +  0 + c) * K + q * 8;
  const bf16* W1 = W + (long)(nbase + 16 + c) * K + q * 8;
  const bf16* W2 = W + (long)(nbase + 32 + c) * K + q * 8;
  const bf16* W3 = W + (long)(nbase + 48 + c) * K + q * 8;

  floatx4 acc0 = {0.f, 0.f, 0.f, 0.f};
  floatx4 acc1 = acc0, acc2 = acc0, acc3 = acc0;
  const int nk = K >> 5;
  for (int kt = 0; kt < nk; ++kt) {
    short8 a;
    floatx4 lo = *reinterpret_cast<const floatx4*>(Af + abase + kt * 32);
    floatx4 hi = *reinterpret_cast<const floatx4*>(Af + abase + kt * 32 + 4);
    #pragma unroll
    for (int r = 0; r < 4; ++r) { a[r] = f2bs(lo[r]); a[4 + r] = f2bs(hi[r]); }
    short8 b0 = *reinterpret_cast<const short8*>(W0 + kt * 32);
    short8 b1 = *reinterpret_cast<const short8*>(W1 + kt * 32);
    short8 b2 = *reinterpret_cast<const short8*>(W2 + kt * 32);
    short8 b3 = *reinterpret_cast<const short8*>(W3 + kt * 32);
    acc0 = mfma_bf16(a, b0, acc0);
    acc1 = mfma_bf16(a, b1, acc1);
    acc2 = mfma_bf16(a, b2, acc2);
    acc3 = mfma_bf16(a, b3, acc3);
  }

  floatx4 accs[4] = {acc0, acc1, acc2, acc3};
  #pragma unroll
  for (int nt = 0; nt < 4; ++nt) {
    const int n = nbase + nt * 16 + c;
    const float bv = bias[n];
    #pragma unroll
    for (int r = 0; r < 4; ++r) {
      const int mrow = mtile * 16 + q * 4 + r;
      out[(long)mrow * 2048 + n] = __float2bfloat16(accs[nt][r] + bv);
    }
  }
}

// ---------------------------------------------------------------------------
// Fused 2-layer persistent recurrence, XCD0-clustered. 512 blocks x 256 thr.
// XCD0: 32 blocks claim tickets (16 L0 + 16 L1), the rest EXIT (frees CUs).
// XCD1-7: heater blocks (DVFS insurance), poll done every ~14us.
// ---------------------------------------------------------------------------
__global__ __launch_bounds__(256)
void lstm_fused(const bf16* __restrict__ wx, const bf16* __restrict__ Ub0,
                const bf16* __restrict__ Wb1, const bf16* __restrict__ Ub1,
                const float* __restrict__ ub0, const float* __restrict__ w1b,
                const float* __restrict__ u1b, float* __restrict__ out,
                u64* __restrict__ payl0, u64* __restrict__ payl1,
                unsigned int* __restrict__ done, unsigned int* __restrict__ claim)
{
  __shared__ char lds[2 * BUFSZ];   // double-buffered shared h staging
  __shared__ int s_ticket;
  if (threadIdx.x == 0) {
    int xcd = 0;
    asm volatile("s_getreg_b32 %0, hwreg(HW_REG_XCC_ID)" : "=s"(xcd));
    int tk = -1;                                 // default: heater (XCD1-7)
    if ((xcd & 7) == 0) {
      unsigned int t = __hip_atomic_fetch_add(claim, 1u, __ATOMIC_RELAXED,
                                              __HIP_MEMORY_SCOPE_AGENT);
      tk = (t < (unsigned)N_TICK) ? (int)t : -2; // XCD0 spare: exit
    }
    s_ticket = tk;
  }
  __syncthreads();
  const int ticket = s_ticket;

  if (ticket == -2) return;   // XCD0 spare block: free the CU for rec waves

  if (ticket < 0) {
    // ---------------- heater (XCD1-7 blocks only) ----------------
    float a0 = (float)threadIdx.x, a1 = a0 + 1.f, a2 = a0 + 2.f, a3 = a0 + 3.f;
    float a4 = a0 + 4.f, a5 = a0 + 5.f, a6 = a0 + 6.f, a7 = a0 + 7.f;
    const float xm = 1.0000001f, ya = 1e-7f;
    int g = 0;
    for (;;) {
      #pragma unroll
      for (int it = 0; it < 64; ++it) {
        asm volatile("v_fmac_f32 %0, %1, %2" : "+v"(a0) : "v"(xm), "v"(ya));
        asm volatile("v_fmac_f32 %0, %1, %2" : "+v"(a1) : "v"(xm), "v"(ya));
        asm volatile("v_fmac_f32 %0, %1, %2" : "+v"(a2) : "v"(xm), "v"(ya));
        asm volatile("v_fmac_f32 %0, %1, %2" : "+v"(a3) : "v"(xm), "v"(ya));
        asm volatile("v_fmac_f32 %0, %1, %2" : "+v"(a4) : "v"(xm), "v"(ya));
        asm volatile("v_fmac_f32 %0, %1, %2" : "+v"(a5) : "v"(xm), "v"(ya));
        asm volatile("v_fmac_f32 %0, %1, %2" : "+v"(a6) : "v"(xm), "v"(ya));
        asm volatile("v_fmac_f32 %0, %1, %2" : "+v"(a7) : "v"(xm), "v"(ya));
      }
      ++g;
      if ((g & 31) == 0) {           // poll rarely: keeps the MALL line quiet
        if (__hip_atomic_load(done, __ATOMIC_RELAXED,
                              __HIP_MEMORY_SCOPE_AGENT) >= (unsigned)N_TICK) break;
      }
      if (g > (1 << 16)) break;
    }
    return;
  }

  // ---------------- recurrence (4 waves of the 32 claimed blocks) ----------
  asm volatile("s_setprio 3" ::: "memory");
  const int wv    = threadIdx.x >> 6;
  const int lane  = threadIdx.x & 63;
  const int q     = lane >> 4;
  const int b     = lane & 15;
  const int layer = ticket >> 4;          // 0..1
  const int grp   = ticket & 15;          // 0..15
  const int blk   = grp * 4 + wv;         // 0..63
  const int jbase = blk * 8;
  const int jj    = jbase + (q & 1) * 4;

  const int row0 = (b < 8) ? (jbase + b) : (512 + jbase + b - 8);           // i | f
  const int row1 = (b < 8) ? (1024 + jbase + b) : (1536 + jbase + b - 8);   // g | o

  float* hh = out + ((layer == 0) ? HH_OFF : HH_OFF + 4096);
  float* cc = out + ((layer == 0) ? CC_OFF : CC_OFF + 4096);

  if (layer == 0) {
    // ---- Layer 0: K=512 (U0 * h1(t-1)) + precomputed wx ----
    short8 a0[16], a1[16];
    {
      const bf16* U0p = Ub0 + (long)row0 * 512 + q * 8;
      const bf16* U1p = Ub0 + (long)row1 * 512 + q * 8;
      #pragma unroll
      for (int kt = 0; kt < 16; ++kt) {
        a0[kt] = *reinterpret_cast<const short8*>(U0p + kt * 32);
        a1[kt] = *reinterpret_cast<const short8*>(U1p + kt * 32);
      }
    }
    float ubi[4], ubf[4], ubg[4], ubo[4];
    #pragma unroll
    for (int r = 0; r < 4; ++r) {
      ubi[r] = ub0[        jj + r];
      ubf[r] = ub0[ 512 + jj + r];
      ubg[r] = ub0[1024 + jj + r];
      ubo[r] = ub0[1536 + jj + r];
    }
    float cst[4] = {0.f, 0.f, 0.f, 0.f};

    // wx prefetch pipeline: regs hold step t while loop body issues t+1.
    const bf16* wxbase = wx + (b & 7) * 2048 + jj;
    short4v vi = *reinterpret_cast<const short4v*>(wxbase);
    short4v vf = *reinterpret_cast<const short4v*>(wxbase + 512);
    short4v vg = *reinterpret_cast<const short4v*>(wxbase + 1024);
    short4v vo = *reinterpret_cast<const short4v*>(wxbase + 1536);

    for (int t = 0; t < T_STEPS; ++t) {
      float wxi[4], wxf[4], wxg[4], wxo[4];
      #pragma unroll
      for (int r = 0; r < 4; ++r) {
        wxi[r] = bs2f(vi[r]); wxf[r] = bs2f(vf[r]);
        wxg[r] = bs2f(vg[r]); wxo[r] = bs2f(vo[r]);
      }
      if (t + 1 < T_STEPS) {
        const bf16* wn = wxbase + (long)(t + 1) * 16384;
        vi = *reinterpret_cast<const short4v*>(wn);
        vf = *reinterpret_cast<const short4v*>(wn + 512);
        vg = *reinterpret_cast<const short4v*>(wn + 1024);
        vo = *reinterpret_cast<const short4v*>(wn + 1536);
      }

      char* buf = lds + (t & 1) * BUFSZ;
      floatx4 acc0 = {0.f, 0.f, 0.f, 0.f};
      floatx4 acc1 = {0.f, 0.f, 0.f, 0.f};

      if (t > 0)
        poll_fetch_q(payl0 + (long)(t - 1) * 1024, wv, lane, buf, STR0, 0);
      __syncthreads();
      if (t > 0) {
        #pragma unroll
        for (int kt = 0; kt < 16; ++kt) {
          short8 hb = *reinterpret_cast<const short8*>(
              buf + (b & 7) * STR0 + kt * 64 + q * 16);
          acc0 = mfma_bf16(a0[kt], hb, acc0);
          acc1 = mfma_bf16(a1[kt], hb, acc1);
        }
      }

      float fsh[4], osh[4];
      #pragma unroll
      for (int r = 0; r < 4; ++r) {
        fsh[r] = __shfl_xor(acc0[r], 32, 64);
        osh[r] = __shfl_xor(acc1[r], 32, 64);
      }

      if (q < 2 && b < 8) {
        short4v hp4; floatx4 hf4, cf4;
        #pragma unroll
        for (int r = 0; r < 4; ++r) {
          const float pi = acc0[r] + wxi[r] + ubi[r];
          const float pf = fsh[r]  + wxf[r] + ubf[r];
          const float pg = acc1[r] + wxg[r] + ubg[r];
          const float po = osh[r]  + wxo[r] + ubo[r];
          const float it = sigm(pi), ft = sigm(pf);
          const float gt = tanhf_(pg), ot = sigm(po);
          const float cv = ft * cst[r] + it * gt;
          cst[r] = cv;
          const float hv = ot * fmaxf(cv, 0.f);
          hf4[r] = hv; cf4[r] = cv; hp4[r] = f2bs(hv);
        }
        union { short4v v; u64 u; } pk; pk.v = hp4;
        cstore(payl0 + (long)t * 1024 + blk * 16 + (b * 2 + (q & 1)), pk.u);
        if (t == T_STEPS - 1) {
          *reinterpret_cast<floatx4*>(hh + b * 512 + jj) = hf4;
          *reinterpret_cast<floatx4*>(cc + b * 512 + jj) = cf4;
        }
      }
    }
  } else {
    // ---- Layer 1: K=1024 ([W1|U1] * [h1(t); h2(t-1)]) ----
    short8 a0[32], a1[32];
    {
      const bf16* W0p = Wb1 + (long)row0 * 512 + q * 8;
      const bf16* W1p = Wb1 + (long)row1 * 512 + q * 8;
      const bf16* U0p = Ub1 + (long)row0 * 512 + q * 8;
      const bf16* U1p = Ub1 + (long)row1 * 512 + q * 8;
      #pragma unroll
      for (int kt = 0; kt < 16; ++kt) {
        a0[kt]      = *reinterpret_cast<const short8*>(W0p + kt * 32);
        a1[kt]      = *reinterpret_cast<const short8*>(W1p + kt * 32);
        a0[16 + kt] = *reinterpret_cast<const short8*>(U0p + kt * 32);
        a1[16 + kt] = *reinterpret_cast<const short8*>(U1p + kt * 32);
      }
    }
    float ubi[4], ubf[4], ubg[4], ubo[4];
    #pragma unroll
    for (int r = 0; r < 4; ++r) {
      ubi[r] = w1b[        jj + r] + u1b[        jj + r];
      ubf[r] = w1b[ 512 + jj + r] + u1b[ 512 + jj + r];
      ubg[r] = w1b[1024 + jj + r] + u1b[1024 + jj + r];
      ubo[r] = w1b[1536 + jj + r] + u1b[1536 + jj + r];
    }
    float cst[4] = {0.f, 0.f, 0.f, 0.f};

    for (int t = 0; t < T_STEPS; ++t) {
      char* buf = lds + (t & 1) * BUFSZ;
      floatx4 acc0 = {0.f, 0.f, 0.f, 0.f};
      floatx4 acc1 = {0.f, 0.f, 0.f, 0.f};

      if (t > 0) {
        poll_fetch_q2(payl0 + (long)t * 1024, payl1 + (long)(t - 1) * 1024,
                      wv, lane, buf);
      } else {
        poll_fetch_q(payl0, wv, lane, buf, STR1, 0);
      }
      __syncthreads();

      #pragma unroll
      for (int kt = 0; kt < 16; ++kt) {
        short8 hb = *reinterpret_cast<const short8*>(
            buf + (b & 7) * STR1 + kt * 64 + q * 16);
        acc0 = mfma_bf16(a0[kt], hb, acc0);
        acc1 = mfma_bf16(a1[kt], hb, acc1);
      }
      if (t > 0) {
        #pragma unroll
        for (int kt = 16; kt < 32; ++kt) {
          short8 hb = *reinterpret_cast<const short8*>(
              buf + (b & 7) * STR1 + kt * 64 + q * 16);
          acc0 = mfma_bf16(a0[kt], hb, acc0);
          acc1 = mfma_bf16(a1[kt], hb, acc1);
        }
      }

      float fsh[4], osh[4];
      #pragma unroll
      for (int r = 0; r < 4; ++r) {
        fsh[r] = __shfl_xor(acc0[r], 32, 64);
        osh[r] = __shfl_xor(acc1[r], 32, 64);
      }

      if (q < 2 && b < 8) {
        short4v hp4; floatx4 hf4, cf4;
        #pragma unroll
        for (int r = 0; r < 4; ++r) {
          const float pi = acc0[r] + ubi[r];
          const float pf = fsh[r]  + ubf[r];
          const float pg = acc1[r] + ubg[r];
          const float po = osh[r]  + ubo[r];
          const float it = sigm(pi), ft = sigm(pf);
          const float gt = tanhf_(pg), ot = sigm(po);
          const float cv = ft * cst[r] + it * gt;
          cst[r] = cv;
          const float hv = ot * fmaxf(cv, 0.f);
          hf4[r] = hv; cf4[r] = cv; hp4[r] = f2bs(hv);
        }
        union { short4v v; u64 u; } pk; pk.v = hp4;
        cstore(payl1 + (long)t * 1024 + blk * 16 + (b * 2 + (q & 1)), pk.u);
        *reinterpret_cast<floatx4*>(out + (long)b * 1048576 + (long)t * 512 + jj) = hf4;
        if (t == T_STEPS - 1) {
          *reinterpret_cast<floatx4*>(hh + b * 512 + jj) = hf4;
          *reinterpret_cast<floatx4*>(cc + b * 512 + jj) = cf4;
        }
      }
    }
  }

  // Signal heaters to exit (one per rec block).
  __syncthreads();
  if (threadIdx.x == 0) {
    __hip_atomic_fetch_add(done, 1u, __ATOMIC_RELAXED, __HIP_MEMORY_SCOPE_AGENT);
  }
}

extern "C" void kernel_launch(void* const* d_in, const int* in_sizes, int n_in,
                              void* d_out, int out_size, void* d_ws, size_t ws_size,
                              hipStream_t stream) {
  (void)in_sizes; (void)n_in; (void)out_size; (void)ws_size;
  const float* x   = (const float*)d_in[0];
  const float* w0w = (const float*)d_in[1];
  const float* w0b = (const float*)d_in[2];
  const float* u0w = (const float*)d_in[3];
  const float* u0b = (const float*)d_in[4];
  const float* w1w = (const float*)d_in[5];
  const float* w1b = (const float*)d_in[6];
  const float* u1w = (const float*)d_in[7];
  const float* u1b = (const float*)d_in[8];
  float* out = (float*)d_out;

  char* ws = (char*)d_ws;
  u64*  payl0 = (u64*)ws;
  u64*  payl1 = (u64*)(ws + (size_t)16777216);
  bf16* Wb0 = (bf16*)(ws + (size_t)33554432);
  bf16* Ub0 = (bf16*)(ws + (size_t)34603008);
  bf16* Wb1 = (bf16*)(ws + (size_t)36700160);
  bf16* Ub1 = (bf16*)(ws + (size_t)38797312);
  bf16* wx  = (bf16*)(ws + (size_t)40894464);
  unsigned int* done = (unsigned int*)(ws + (size_t)115343360);

  // Sentinel-fill payload arrays; zero the done+claim counters.
  hipMemsetAsync(ws, 0xFF, (size_t)33554432, stream);
  hipMemsetAsync(done, 0, 64, stream);

  // Weight conversions fp32 -> bf16.
  cvt_f32_bf16<<<512,  256, 0, stream>>>(w0w, Wb0, 524288);
  cvt_f32_bf16<<<1024, 256, 0, stream>>>(u0w, Ub0, 1048576);
  cvt_f32_bf16<<<1024, 256, 0, stream>>>(w1w, Wb1, 1048576);
  cvt_f32_bf16<<<1024, 256, 0, stream>>>(u1w, Ub1, 1048576);

  // Layer-0 input projection.
  dim3 gg(1024, 8, 1);
  gemm_proj<<<gg, 256, 0, stream>>>(x, Wb0, w0b, wx, 256, 2048 * 256, 256);

  // Fused 2-layer recurrence (XCD0 rec, XCD1-7 heat) + heaters.
  lstm_fused<<<N_BLK, 256, 0, stream>>>(wx, Ub0, Wb1, Ub1, u0b, w1b, u1b,
                                        out, payl0, payl1, done, done + 1);
}